// Round 11
// baseline (62.261 us; speedup 1.0000x reference)
//
#include <hip/hip_runtime.h>
#include <hip/hip_bf16.h>
#include <hip/hip_fp16.h>
#include <stdint.h>

typedef __bf16 bf16_8 __attribute__((ext_vector_type(8)));
typedef float f32x4 __attribute__((ext_vector_type(4)));
typedef unsigned int u32;
typedef unsigned short u16;

// Problem dims (fixed): B=8, R=4, N=1024, D_IN=D_OUT=256.
// Inputs FP32 (per reference); internal GEMMs bf16 MFMA; partial fp16;
// output FP32.

__device__ __forceinline__ u16 f2b(float f) {
    return __builtin_bit_cast(u16, __float2bfloat16(f));
}
__device__ __forceinline__ u16 f2h(float f) {
    return __builtin_bit_cast(u16, __float2half(f));
}

// LDS tile: rows x 32 k (bf16) as 16B chunks, 4 chunks/row (64B row stride).
// Chunk (row,g) at index row*4 + (g ^ ((row>>1)&3)). Frag reads (fixed g, 16
// consecutive rows) measured conflict-free (R2-R10 profiles: 0 conflicts).
__device__ __forceinline__ u32 swz_off(u32 row, u32 g) {
    return (row * 4u + (g ^ ((row >> 1) & 3u))) * 16u;
}

__device__ __forceinline__ void gload_lds16(const void* g, void* l) {
    __builtin_amdgcn_global_load_lds((const __attribute__((address_space(1))) void*)g,
                                     (__attribute__((address_space(3))) void*)l, 16, 0, 0);
}

// Compiler-only memory scheduling fence: pins VMEM issue-order regions so
// counted s_waitcnt vmcnt(N) bookkeeping is deterministic.
__device__ __forceinline__ void memfence_sched() { asm volatile("" ::: "memory"); }

__device__ __forceinline__ uint4 pack8(float4 a, float4 b) {
    uint4 pk;
    pk.x = (u32)f2b(a.x) | ((u32)f2b(a.y) << 16);
    pk.y = (u32)f2b(a.z) | ((u32)f2b(a.w) << 16);
    pk.z = (u32)f2b(b.x) | ((u32)f2b(b.y) << 16);
    pk.w = (u32)f2b(b.z) | ((u32)f2b(b.w) << 16);
    return pk;
}

// Wt[r][dout][din] = bf16(W[r][din][dout])
__global__ __launch_bounds__(256) void wt_cvt_kernel(const float* W, u16* Wt) {
    const u32 idx = blockIdx.x * 256u + threadIdx.x;  // 262144 total
    const u32 r = idx >> 16, rem = idx & 65535u, dout = rem >> 8, din = rem & 255u;
    Wt[idx] = f2b(W[(r << 16) + (din << 8) + dout]);
}

// Yt[b,r,dout,j] = bf16( sum_din Wt[r,dout,din] * text[b,j,din] )
// TEXT READ DIRECTLY (fp32 -> bf16 in-register; textb intermediate removed,
// -8 MB HBM). A (Wt) via gload_lds; B (text) reg-staged with the adj
// kernel's proven map: thread t owns chunks t and t+256 (rows t>>2 and
// t>>2+64, chunk lane t&3), source k-offset pre-swizzled, both ds_write
// instructions lane-contiguous (conflict-free). Counted-vmcnt depth-2:
// 6 VMEM/iter (4x B float4 + 2x A gload_lds, tile ks+2), vmcnt(6).
// Invariant entering iter ks: bufA[ks%3]=A(ks), bufB[ks&1]=B(ks),
// rB[(ks+1)&1]=B(ks+1) regs; outstanding = {B(ks+1)x4, A(ks+1)x2}.
// XCD remap: batch b -> XCD b (text[b] 1 MB + Yt[b] stay in one L2).
__global__ __launch_bounds__(256) void y_gemm_kernel(const u16* Wt, const float* text,
                                                     u16* Yt) {
    __shared__ char smem[40960];
    char* bufA = smem;                 // 3 x 8192 (128 rows x 32k bf16)
    char* bufB = smem + 24576;         // 2 x 8192

    const u32 raw = blockIdx.x;        // 512 = 8 XCDs x 64
    const u32 bx = (raw & 7u) * 64u + (raw >> 3);
    const u32 n0 = (bx & 7u) * 128u;
    const u32 m0 = ((bx >> 3) & 1u) * 128u;
    const u32 r  = (bx >> 4) & 3u;
    const u32 b  = bx >> 6;
    const u16* pA = Wt + (size_t)r * 65536u + (size_t)m0 * 256u;
    const float* pT = text + (size_t)b * 262144u + (size_t)n0 * 256u;

    const u32 t    = threadIdx.x;
    const u32 lane = t & 63u;
    const u32 w    = t >> 6;
    const u32 wm   = (w >> 1) * 64u;
    const u32 wn   = (w & 1u) * 64u;
    const u32 waveByte = (t & 192u) * 16u;
    const u32 fr = lane & 15u;
    const u32 fg = lane >> 4;

    // A gload map (verbatim R9/R10): rows t>>2 and +64, pre-swizzled chunk.
    const u32 arow0 = t >> 2;
    const u32 agg0  = (t & 3u) ^ ((arow0 >> 1) & 3u);
    const u32 arow1 = arow0 + 64u;
    const u32 agg1  = ((t + 256u) & 3u) ^ ((arow1 >> 1) & 3u);
    const u16* a0p = pA + (size_t)arow0 * 256u + agg0 * 8u;
    const u16* a1p = pA + (size_t)arow1 * 256u + agg1 * 8u;

    // B reg-stage map (adj-kernel pattern): thread t owns chunk t (row
    // brow0=t>>2, lane c=t&3) and chunk t+256 (row brow0+64, same c);
    // global source k-offset pre-swizzled per row (involution with frag read).
    const u32 brow0 = t >> 2;
    const u32 bc    = t & 3u;
    const u32 bsw0  = (brow0 >> 1) & 3u;
    const u32 bsw1  = ((brow0 + 64u) >> 1) & 3u;
    const float* bSrc0 = pT + (size_t)brow0 * 256u + (bc ^ bsw0) * 8u;
    const float* bSrc1 = pT + (size_t)(brow0 + 64u) * 256u + (bc ^ bsw1) * 8u;

    f32x4 acc[4][4];
#pragma unroll
    for (int i = 0; i < 4; ++i)
#pragma unroll
        for (int j = 0; j < 4; ++j) acc[i][j] = (f32x4){0.f, 0.f, 0.f, 0.f};

    float4 rB[2][4];

    auto loadB = [&](float4* dst, u32 kt) {
        dst[0] = *(const float4*)(bSrc0 + kt * 32u);
        dst[1] = *(const float4*)(bSrc0 + kt * 32u + 4u);
        dst[2] = *(const float4*)(bSrc1 + kt * 32u);
        dst[3] = *(const float4*)(bSrc1 + kt * 32u + 4u);
    };
    auto stageA = [&](u32 kt, u32 slot) {
        gload_lds16(a0p + kt * 32u, bufA + slot * 8192u + waveByte);
        gload_lds16(a1p + kt * 32u, bufA + slot * 8192u + waveByte + 4096u);
    };
    auto packB = [&](const float4* rs, char* dst) {
        *(uint4*)(dst + t * 16u) = pack8(rs[0], rs[1]);            // chunk t
        *(uint4*)(dst + 4096u + t * 16u) = pack8(rs[2], rs[3]);    // chunk t+256
    };
    auto do_mfma = [&](u32 slotA, u32 slotB) {
        char* curA = bufA + slotA * 8192u;
        char* curB = bufB + slotB * 8192u;
        bf16_8 af[4], bfv[4];
#pragma unroll
        for (int mt = 0; mt < 4; ++mt) {
            uint4 v = *(const uint4*)(curA + swz_off(wm + (u32)mt * 16u + fr, fg));
            af[mt] = __builtin_bit_cast(bf16_8, v);
        }
#pragma unroll
        for (int nt = 0; nt < 4; ++nt) {
            uint4 v = *(const uint4*)(curB + swz_off(wn + (u32)nt * 16u + fr, fg));
            bfv[nt] = __builtin_bit_cast(bf16_8, v);
        }
#pragma unroll
        for (int mt = 0; mt < 4; ++mt)
#pragma unroll
            for (int nt = 0; nt < 4; ++nt)
                acc[mt][nt] = __builtin_amdgcn_mfma_f32_16x16x32_bf16(af[mt], bfv[nt],
                                                                      acc[mt][nt], 0, 0, 0);
    };

    // Prologue: issue {B0x4,A0x2} then {B1x4,A1x2}; pack B0; keep 6 in flight.
    loadB(rB[0], 0u);
    stageA(0u, 0u);
    memfence_sched();
    loadB(rB[1], 1u);
    stageA(1u, 1u);
    memfence_sched();
    packB(rB[0], bufB);    // implicit wait drains B(0)x4 only
    asm volatile("s_waitcnt vmcnt(6) lgkmcnt(0)" ::: "memory");  // A(0) landed
    __builtin_amdgcn_s_barrier();

    // Main: ks=0..5, compute tile ks, issue tile ks+2 (6 VMEM ops).
#pragma unroll 6
    for (int ks = 0; ks < 6; ++ks) {
        const u32 cB = (u32)ks & 1u, nB = cB ^ 1u;
        packB(rB[nB], bufB + nB * 8192u);              // B(ks+1) -> LDS
        loadB(rB[cB], (u32)(ks + 2));                  // 4 ops
        stageA((u32)(ks + 2), (u32)((ks + 2) % 3));    // 2 ops
        do_mfma((u32)(ks % 3), cB);
        asm volatile("s_waitcnt vmcnt(6) lgkmcnt(0)" ::: "memory");
        __builtin_amdgcn_s_barrier();
    }
    // Peel ks=6: pack B(7), no new issues.
    packB(rB[1], bufB + 8192u);
    do_mfma(0u, 0u);                    // tile 6: bufA[6%3=0], bufB[0]
    asm volatile("s_waitcnt vmcnt(0) lgkmcnt(0)" ::: "memory");
    __builtin_amdgcn_s_barrier();
    // Peel ks=7.
    do_mfma(1u, 1u);                    // tile 7: bufA[7%3=1], bufB[1]

    const u32 rit = fg * 4u, cit = fr;  // C: row=(lane>>4)*4+reg
    u16* yb = Yt + (size_t)(b * 4u + r) * 262144u;
#pragma unroll
    for (int mt = 0; mt < 4; ++mt)
#pragma unroll
        for (int nt = 0; nt < 4; ++nt) {
            const u32 m = m0 + wm + (u32)mt * 16u + rit;
            const u32 n = n0 + wn + (u32)nt * 16u + cit;
#pragma unroll
            for (int rg = 0; rg < 4; ++rg)
                yb[(size_t)(m + (u32)rg) * 1024u + n] = f2b(acc[mt][nt][rg]);
        }
}

// partial[b,r,i,d] = fp16( inv[b,r,i] * sum_j adj[b,r,i,j]*Yt[b,r,d,j] )
// R10's verified kernel VERBATIM. BM=128 x full d=256, BK=32, K=1024,
// grid 256 = 8b x 4r x 8 i-tiles (adj read exactly once). Depth-2
// counted-vmcnt pipeline: 4 VMEM/iter, vmcnt(4).
__global__ __launch_bounds__(512, 2) void adj_gemm_partial(const float* adj,
                                                           const u16* Yt,
                                                           u16* partial) {
    __shared__ char smem[66048];
    char* bufA = smem;                     // 2 x 8192  (128 rows x 32k bf16)
    char* bufB = smem + 16384;             // 3 x 16384 (256 rows x 32k bf16)
    float* sInv = (float*)(smem + 65536);  // 128 row inverses

    // XCD-contiguous bijective remap (256 = 8 XCDs x 32): XCD x gets batch
    // b = x entirely -> Yt[b] (2 MB) stays in that XCD's 4 MB L2.
    const u32 raw = blockIdx.x;
    const u32 bx = (raw & 7u) * 32u + (raw >> 3);
    const u32 i0 = (bx & 7u) * 128u;
    const u32 r  = (bx >> 3) & 3u;
    const u32 b  = bx >> 5;

    const float* pA = adj + (((size_t)(b * 4u + r)) << 20) + (size_t)i0 * 1024u;
    const u16*   pB = Yt + (((size_t)(b * 4u + r)) << 18);

    const u32 t = threadIdx.x, lane = t & 63u, w = t >> 6;
    const u32 wm = (w >> 2) * 64u;         // 2 M-groups (0/64)
    const u32 wn = (w & 3u) * 64u;         // 4 N-groups (0..192)
    const u32 fr = lane & 15u, fg = lane >> 4;

    // A staging map: row sRow = t>>2 (0..127), linear chunk cLin = t&3; the
    // global source chunk is cLin ^ rowparity so the linear ds_write at t*16
    // lands where the swizzled frag read expects it.
    const u32 sRow = t >> 2;
    const u32 cSwz = (t & 3u) ^ ((sRow >> 1) & 3u);
    const float* aSrc = pA + (size_t)sRow * 1024u + cSwz * 8u;

    // B staging map (verbatim R5/R8): chunks t and t+512 of the 256-row tile,
    // linear LDS dst (wave base + lane*16), global source pre-swizzled.
    const u32 brow0 = t >> 2;                              // 0..127
    const u32 brow1 = (t + 512u) >> 2;                     // 128..255
    const u32 bg0 = (t & 3u) ^ ((brow0 >> 1) & 3u);
    const u32 bg1 = (t & 3u) ^ ((brow1 >> 1) & 3u);
    const u16* b0p = pB + (size_t)brow0 * 1024u + bg0 * 8u;
    const u16* b1p = pB + (size_t)brow1 * 1024u + bg1 * 8u;
    const u32 waveB = (t & 448u) * 16u;    // wave-uniform LDS byte base

    f32x4 acc[4][4];
#pragma unroll
    for (int i = 0; i < 4; ++i)
#pragma unroll
        for (int j = 0; j < 4; ++j) acc[i][j] = (f32x4){0.f, 0.f, 0.f, 0.f};

    float s0 = 0.f;
    float4 rA[2][2];

    auto loadA = [&](float4* dst, u32 kt) {
        dst[0] = *(const float4*)(aSrc + kt * 32u);
        dst[1] = *(const float4*)(aSrc + kt * 32u + 4u);
    };
    auto stageB = [&](u32 kt, char* dst) {
        gload_lds16(b0p + kt * 32u, dst + waveB);
        gload_lds16(b1p + kt * 32u, dst + 8192u + waveB);
    };
    auto packA = [&](const float4* a2, char* dst) {
        s0 += (a2[0].x + a2[0].y + a2[0].z + a2[0].w)
            + (a2[1].x + a2[1].y + a2[1].z + a2[1].w);
        *(uint4*)(dst + t * 16u) = pack8(a2[0], a2[1]);
    };
    auto do_mfma = [&](char* curA, char* curB) {
        bf16_8 af[4], bfv[4];
#pragma unroll
        for (int mt = 0; mt < 4; ++mt) {
            uint4 v = *(const uint4*)(curA + swz_off(wm + (u32)mt * 16u + fr, fg));
            af[mt] = __builtin_bit_cast(bf16_8, v);
        }
#pragma unroll
        for (int nt = 0; nt < 4; ++nt) {
            uint4 v = *(const uint4*)(curB + swz_off(wn + (u32)nt * 16u + fr, fg));
            bfv[nt] = __builtin_bit_cast(bf16_8, v);
        }
#pragma unroll
        for (int mt = 0; mt < 4; ++mt)
#pragma unroll
            for (int nt = 0; nt < 4; ++nt)
                acc[mt][nt] = __builtin_amdgcn_mfma_f32_16x16x32_bf16(af[mt], bfv[nt],
                                                                      acc[mt][nt], 0, 0, 0);
    };

    // ---- Prologue: issue {A0x2,B0x2} then {A1x2,B1x2}; pack A0; keep 4 in flight.
    loadA(rA[0], 0u);
    stageB(0u, bufB);
    memfence_sched();
    loadA(rA[1], 1u);
    stageB(1u, bufB + 16384u);
    memfence_sched();
    packA(rA[0], bufA);    // implicit wait drains A(0)x2 only
    asm volatile("s_waitcnt vmcnt(4) lgkmcnt(0)" ::: "memory");  // B(0) landed
    __builtin_amdgcn_s_barrier();

    // ---- Main: ks=0..29, compute tile ks, issue tile ks+2 (4 VMEM ops).
#pragma unroll 6
    for (int ks = 0; ks < 30; ++ks) {
        const u32 cA = (u32)ks & 1u, nA = cA ^ 1u;
        packA(rA[nA], bufA + nA * 8192u);              // A(ks+1) -> LDS
        loadA(rA[cA], (u32)(ks + 2));                  // 2 ops
        stageB((u32)(ks + 2), bufB + (u32)((ks + 2) % 3) * 16384u);  // 2 ops
        do_mfma(bufA + cA * 8192u, bufB + (u32)(ks % 3) * 16384u);
        asm volatile("s_waitcnt vmcnt(4) lgkmcnt(0)" ::: "memory");
        __builtin_amdgcn_s_barrier();
    }
    // ---- Peel ks=30: pack A(31), no new issues.
    packA(rA[1], bufA + 8192u);
    do_mfma(bufA, bufB);                               // tile 30: bufB[30%3=0]
    asm volatile("s_waitcnt vmcnt(0) lgkmcnt(0)" ::: "memory");
    __builtin_amdgcn_s_barrier();
    // ---- Peel ks=31.
    do_mfma(bufA + 8192u, bufB + 16384u);              // tile 31: bufB[1]

    // rowsum: 4 consecutive threads (t&3) hold k-slices of row sRow
    s0 += __shfl_down(s0, 2, 64);
    s0 += __shfl_down(s0, 1, 64);
    if ((t & 3u) == 0u) sInv[sRow] = (s0 == 0.f) ? 0.f : 1.f / s0;
    __syncthreads();

    u16* pp = partial + (((size_t)(b * 4u + r)) << 18) + (size_t)i0 * 256u;
#pragma unroll
    for (int mt = 0; mt < 4; ++mt)
#pragma unroll
        for (int rg = 0; rg < 4; ++rg) {
            const u32 mRow = wm + (u32)mt * 16u + fg * 4u + (u32)rg;
            const float inv = sInv[mRow];
#pragma unroll
            for (int nt = 0; nt < 4; ++nt)
                pp[(size_t)mRow * 256u + wn + (u32)nt * 16u + fr] =
                    f2h(acc[mt][nt][rg] * inv);
        }
}

// out[b,i,d] = bias[d] + sum_r fp32(partial_h[b,r,i,d]); 8 elems/thread.
__global__ __launch_bounds__(256) void reduce_kernel(const u16* partial,
                                                     const float* bias, float* out) {
    const u32 i8 = blockIdx.x * 256u + threadIdx.x;   // 262144 total
    const u32 b = i8 >> 15;
    const u32 rem8 = (i8 & 32767u) * 8u;              // elem offset within batch
    const u32 d0 = rem8 & 255u;

    const float4 bv0 = *(const float4*)(bias + d0);
    const float4 bv1 = *(const float4*)(bias + d0 + 4u);
    float s[8] = {bv0.x, bv0.y, bv0.z, bv0.w, bv1.x, bv1.y, bv1.z, bv1.w};

#pragma unroll
    for (u32 r = 0; r < 4u; ++r) {
        const uint4 v = *(const uint4*)(partial + (((size_t)(b * 4u + r)) << 18) + rem8);
        const u16* h = (const u16*)&v;
#pragma unroll
        for (int j = 0; j < 8; ++j)
            s[j] += __half2float(__builtin_bit_cast(__half, h[j]));
    }
    const float4 o0 = {s[0], s[1], s[2], s[3]};
    const float4 o1 = {s[4], s[5], s[6], s[7]};
    ((float4*)out)[i8 * 2u] = o0;
    ((float4*)out)[i8 * 2u + 1u] = o1;
}

extern "C" void kernel_launch(void* const* d_in, const int* in_sizes, int n_in,
                              void* d_out, int out_size, void* d_ws, size_t ws_size,
                              hipStream_t stream) {
    const float* text = (const float*)d_in[0];  // [8,1024,256] fp32
    const float* adj  = (const float*)d_in[1];  // [8,4,1024,1024] fp32
    const float* wgt  = (const float*)d_in[2];  // [4,256,256] fp32
    const float* bias = (const float*)d_in[3];  // [256] fp32
    float* out = (float*)d_out;                 // [8,1024,256] fp32

    char* ws = (char*)d_ws;
    u16* Yt      = (u16*)ws;                    // 16 MB  bf16 [B,R,256,1024]
    u16* Wt      = (u16*)(ws + 16777216u);      // 512 KB bf16 [R,256,256]
    u16* partial = (u16*)(ws + 17301504u);      // 16 MB  fp16 [B,R,N,256]

    wt_cvt_kernel<<<1024, 256, 0, stream>>>(wgt, Wt);
    y_gemm_kernel<<<512, 256, 0, stream>>>(Wt, text, Yt);
    adj_gemm_partial<<<256, 512, 0, stream>>>(adj, Yt, partial);
    reduce_kernel<<<1024, 256, 0, stream>>>(partial, bias, out);
}

// Round 12
// 59.357 us; speedup vs baseline: 1.0489x; 1.0489x over previous
//
#include <hip/hip_runtime.h>
#include <hip/hip_bf16.h>
#include <hip/hip_fp16.h>
#include <stdint.h>

typedef __bf16 bf16_8 __attribute__((ext_vector_type(8)));
typedef float f32x4 __attribute__((ext_vector_type(4)));
typedef unsigned int u32;
typedef unsigned short u16;

// Problem dims (fixed): B=8, R=4, N=1024, D_IN=D_OUT=256.
// Inputs FP32 (per reference); internal GEMMs bf16 MFMA; partial fp16;
// output FP32.  [R12 = revert to the best-verified R10 configuration.]

__device__ __forceinline__ u16 f2b(float f) {
    return __builtin_bit_cast(u16, __float2bfloat16(f));
}
__device__ __forceinline__ u16 f2h(float f) {
    return __builtin_bit_cast(u16, __float2half(f));
}

// LDS tile: rows x 32 k (bf16) as 16B chunks, 4 chunks/row (64B row stride).
// Chunk (row,g) at index row*4 + (g ^ ((row>>1)&3)). Frag reads (fixed g, 16
// consecutive rows) measured conflict-free (R2-R10 profiles: 0 conflicts).
__device__ __forceinline__ u32 swz_off(u32 row, u32 g) {
    return (row * 4u + (g ^ ((row >> 1) & 3u))) * 16u;
}

__device__ __forceinline__ void gload_lds16(const void* g, void* l) {
    __builtin_amdgcn_global_load_lds((const __attribute__((address_space(1))) void*)g,
                                     (__attribute__((address_space(3))) void*)l, 16, 0, 0);
}

// Compiler-only memory scheduling fence: pins VMEM issue-order regions so
// counted s_waitcnt vmcnt(N) bookkeeping is deterministic.
__device__ __forceinline__ void memfence_sched() { asm volatile("" ::: "memory"); }

__device__ __forceinline__ uint4 pack8(float4 a, float4 b) {
    uint4 pk;
    pk.x = (u32)f2b(a.x) | ((u32)f2b(a.y) << 16);
    pk.y = (u32)f2b(a.z) | ((u32)f2b(a.w) << 16);
    pk.z = (u32)f2b(b.x) | ((u32)f2b(b.y) << 16);
    pk.w = (u32)f2b(b.z) | ((u32)f2b(b.w) << 16);
    return pk;
}

// Merged prep: textb = bf16(text) [layout preserved]; Wt[r][dout][din] =
// bf16(W[r][din][dout]). One dispatch instead of two.
__global__ __launch_bounds__(256) void prep_cvt_kernel(const float* text, u16* textb,
                                                       const float* W, u16* Wt) {
    const u32 bid = blockIdx.x;
    if (bid < 1024u) {
        const u32 i8 = bid * 256u + threadIdx.x;         // 262144 total
        const float4 a = ((const float4*)text)[i8 * 2u];
        const float4 b = ((const float4*)text)[i8 * 2u + 1u];
        ((uint4*)textb)[i8] = pack8(a, b);
    } else {
        const u32 idx = (bid - 1024u) * 256u + threadIdx.x;  // 262144 total
        const u32 r = idx >> 16, rem = idx & 65535u, dout = rem >> 8, din = rem & 255u;
        Wt[idx] = f2b(W[(r << 16) + (din << 8) + dout]);
    }
}

// Yt[b,r,dout,j] = bf16( sum_din Wt[r,dout,din] * textb[b,j,din] )
// Counted-vmcnt depth-2 pipeline (R5/R8 skeleton, both operands gload_lds);
// correctness-proven R9/R10.
__global__ __launch_bounds__(256) void y_gemm_kernel(const u16* Wt, const u16* textb,
                                                     u16* Yt) {
    __shared__ char smem[49152];
    char* bufA = smem;                 // 3 x 8192
    char* bufB = smem + 24576;         // 3 x 8192

    const u32 bx = blockIdx.x;                 // 512 blocks: b(3)|r(2)|m(1)|n(3)
    const u32 n0 = (bx & 7u) * 128u;
    const u32 m0 = ((bx >> 3) & 1u) * 128u;
    const u32 r  = (bx >> 4) & 3u;
    const u32 b  = bx >> 6;
    const u16* pA = Wt + (size_t)r * 65536u + (size_t)m0 * 256u;
    const u16* pB = textb + (size_t)b * 262144u + (size_t)n0 * 256u;

    const u32 t    = threadIdx.x;
    const u32 lane = t & 63u;
    const u32 w    = t >> 6;
    const u32 wm   = (w >> 1) * 64u;
    const u32 wn   = (w & 1u) * 64u;
    const u32 waveByte = (t & 192u) * 16u;
    const u32 row0 = t >> 2;
    const u32 gg0  = (t & 3u) ^ ((row0 >> 1) & 3u);
    const u32 row1 = row0 + 64u;
    const u32 gg1  = ((t + 256u) & 3u) ^ ((row1 >> 1) & 3u);
    const u32 fr = lane & 15u;
    const u32 fg = lane >> 4;

    const u16* a0p = pA + (size_t)row0 * 256u + gg0 * 8u;
    const u16* a1p = pA + (size_t)row1 * 256u + gg1 * 8u;
    const u16* b0p = pB + (size_t)row0 * 256u + gg0 * 8u;
    const u16* b1p = pB + (size_t)row1 * 256u + gg1 * 8u;

    f32x4 acc[4][4];
#pragma unroll
    for (int i = 0; i < 4; ++i)
#pragma unroll
        for (int j = 0; j < 4; ++j) acc[i][j] = (f32x4){0.f, 0.f, 0.f, 0.f};

    auto stage = [&](u32 ks, u32 slot) {
        const u32 k0 = ks * 32u;
        gload_lds16(a0p + k0, bufA + slot * 8192u + waveByte);
        gload_lds16(a1p + k0, bufA + slot * 8192u + waveByte + 4096u);
        gload_lds16(b0p + k0, bufB + slot * 8192u + waveByte);
        gload_lds16(b1p + k0, bufB + slot * 8192u + waveByte + 4096u);
    };
    auto do_mfma = [&](u32 slot) {
        char* curA = bufA + slot * 8192u;
        char* curB = bufB + slot * 8192u;
        bf16_8 af[4], bfv[4];
#pragma unroll
        for (int mt = 0; mt < 4; ++mt) {
            uint4 v = *(const uint4*)(curA + swz_off(wm + (u32)mt * 16u + fr, fg));
            af[mt] = __builtin_bit_cast(bf16_8, v);
        }
#pragma unroll
        for (int nt = 0; nt < 4; ++nt) {
            uint4 v = *(const uint4*)(curB + swz_off(wn + (u32)nt * 16u + fr, fg));
            bfv[nt] = __builtin_bit_cast(bf16_8, v);
        }
#pragma unroll
        for (int mt = 0; mt < 4; ++mt)
#pragma unroll
            for (int nt = 0; nt < 4; ++nt)
                acc[mt][nt] = __builtin_amdgcn_mfma_f32_16x16x32_bf16(af[mt], bfv[nt],
                                                                      acc[mt][nt], 0, 0, 0);
    };

    // Prologue: issue tiles 0,1; drain tile 0 only (vmcnt(4)).
    stage(0u, 0u);
    memfence_sched();
    stage(1u, 1u);
    memfence_sched();
    asm volatile("s_waitcnt vmcnt(4)" ::: "memory");
    __builtin_amdgcn_s_barrier();

    // Main: ks=0..5, issue ks+2, compute ks; vmcnt(4) leaves ks+2 in flight.
#pragma unroll 6
    for (int ks = 0; ks < 6; ++ks) {
        stage((u32)(ks + 2), (u32)((ks + 2) % 3));
        memfence_sched();
        do_mfma((u32)(ks % 3));
        asm volatile("s_waitcnt vmcnt(4) lgkmcnt(0)" ::: "memory");
        __builtin_amdgcn_s_barrier();
    }
    // Peel ks=6: no issue; drain tile 7.
    do_mfma(0u);                        // 6 % 3 = 0
    asm volatile("s_waitcnt vmcnt(0) lgkmcnt(0)" ::: "memory");
    __builtin_amdgcn_s_barrier();
    // Peel ks=7.
    do_mfma(1u);                        // 7 % 3 = 1

    const u32 rit = fg * 4u, cit = fr;  // C: row=(lane>>4)*4+reg
    u16* yb = Yt + (size_t)(b * 4u + r) * 262144u;
#pragma unroll
    for (int mt = 0; mt < 4; ++mt)
#pragma unroll
        for (int nt = 0; nt < 4; ++nt) {
            const u32 m = m0 + wm + (u32)mt * 16u + rit;
            const u32 n = n0 + wn + (u32)nt * 16u + cit;
#pragma unroll
            for (int rg = 0; rg < 4; ++rg)
                yb[(size_t)(m + (u32)rg) * 1024u + n] = f2b(acc[mt][nt][rg]);
        }
}

// partial[b,r,i,d] = fp16( inv[b,r,i] * sum_j adj[b,r,i,j]*Yt[b,r,d,j] )
//
// R10's verified kernel VERBATIM. BM=128 x full d=256, BK=32, K=1024,
// grid 256 = 8b x 4r x 8 i-tiles (adj read exactly once). Depth-2
// counted-vmcnt pipeline: 4 VMEM/iter (2x A float4 + 2x B gload_lds, tile
// ks+2), vmcnt(4). At ~6.7 TB/s CU-side service for its 268 MB, this
// kernel sits at the measured chip streaming ceiling (fillBuffer = 7.0).
__global__ __launch_bounds__(512, 2) void adj_gemm_partial(const float* adj,
                                                           const u16* Yt,
                                                           u16* partial) {
    __shared__ char smem[66048];
    char* bufA = smem;                     // 2 x 8192  (128 rows x 32k bf16)
    char* bufB = smem + 16384;             // 3 x 16384 (256 rows x 32k bf16)
    float* sInv = (float*)(smem + 65536);  // 128 row inverses

    // XCD-contiguous bijective remap (256 = 8 XCDs x 32): XCD x gets batch
    // b = x entirely -> Yt[b] (2 MB) stays in that XCD's 4 MB L2.
    const u32 raw = blockIdx.x;
    const u32 bx = (raw & 7u) * 32u + (raw >> 3);
    const u32 i0 = (bx & 7u) * 128u;
    const u32 r  = (bx >> 3) & 3u;
    const u32 b  = bx >> 5;

    const float* pA = adj + (((size_t)(b * 4u + r)) << 20) + (size_t)i0 * 1024u;
    const u16*   pB = Yt + (((size_t)(b * 4u + r)) << 18);

    const u32 t = threadIdx.x, lane = t & 63u, w = t >> 6;
    const u32 wm = (w >> 2) * 64u;         // 2 M-groups (0/64)
    const u32 wn = (w & 3u) * 64u;         // 4 N-groups (0..192)
    const u32 fr = lane & 15u, fg = lane >> 4;

    // A staging map: row sRow = t>>2 (0..127), linear chunk cLin = t&3; the
    // global source chunk is cLin ^ rowparity so the linear ds_write at t*16
    // lands where the swizzled frag read expects it.
    const u32 sRow = t >> 2;
    const u32 cSwz = (t & 3u) ^ ((sRow >> 1) & 3u);
    const float* aSrc = pA + (size_t)sRow * 1024u + cSwz * 8u;

    // B staging map (verbatim R5/R8): chunks t and t+512 of the 256-row tile,
    // linear LDS dst (wave base + lane*16), global source pre-swizzled.
    const u32 brow0 = t >> 2;                              // 0..127
    const u32 brow1 = (t + 512u) >> 2;                     // 128..255
    const u32 bg0 = (t & 3u) ^ ((brow0 >> 1) & 3u);
    const u32 bg1 = (t & 3u) ^ ((brow1 >> 1) & 3u);
    const u16* b0p = pB + (size_t)brow0 * 1024u + bg0 * 8u;
    const u16* b1p = pB + (size_t)brow1 * 1024u + bg1 * 8u;
    const u32 waveB = (t & 448u) * 16u;    // wave-uniform LDS byte base

    f32x4 acc[4][4];
#pragma unroll
    for (int i = 0; i < 4; ++i)
#pragma unroll
        for (int j = 0; j < 4; ++j) acc[i][j] = (f32x4){0.f, 0.f, 0.f, 0.f};

    float s0 = 0.f;
    float4 rA[2][2];

    auto loadA = [&](float4* dst, u32 kt) {
        dst[0] = *(const float4*)(aSrc + kt * 32u);
        dst[1] = *(const float4*)(aSrc + kt * 32u + 4u);
    };
    auto stageB = [&](u32 kt, char* dst) {
        gload_lds16(b0p + kt * 32u, dst + waveB);
        gload_lds16(b1p + kt * 32u, dst + 8192u + waveB);
    };
    auto packA = [&](const float4* a2, char* dst) {
        s0 += (a2[0].x + a2[0].y + a2[0].z + a2[0].w)
            + (a2[1].x + a2[1].y + a2[1].z + a2[1].w);
        *(uint4*)(dst + t * 16u) = pack8(a2[0], a2[1]);
    };
    auto do_mfma = [&](char* curA, char* curB) {
        bf16_8 af[4], bfv[4];
#pragma unroll
        for (int mt = 0; mt < 4; ++mt) {
            uint4 v = *(const uint4*)(curA + swz_off(wm + (u32)mt * 16u + fr, fg));
            af[mt] = __builtin_bit_cast(bf16_8, v);
        }
#pragma unroll
        for (int nt = 0; nt < 4; ++nt) {
            uint4 v = *(const uint4*)(curB + swz_off(wn + (u32)nt * 16u + fr, fg));
            bfv[nt] = __builtin_bit_cast(bf16_8, v);
        }
#pragma unroll
        for (int mt = 0; mt < 4; ++mt)
#pragma unroll
            for (int nt = 0; nt < 4; ++nt)
                acc[mt][nt] = __builtin_amdgcn_mfma_f32_16x16x32_bf16(af[mt], bfv[nt],
                                                                      acc[mt][nt], 0, 0, 0);
    };

    // ---- Prologue: issue {A0x2,B0x2} then {A1x2,B1x2}; pack A0; keep 4 in flight.
    loadA(rA[0], 0u);
    stageB(0u, bufB);
    memfence_sched();
    loadA(rA[1], 1u);
    stageB(1u, bufB + 16384u);
    memfence_sched();
    packA(rA[0], bufA);    // implicit wait drains A(0)x2 only
    asm volatile("s_waitcnt vmcnt(4) lgkmcnt(0)" ::: "memory");  // B(0) landed
    __builtin_amdgcn_s_barrier();

    // ---- Main: ks=0..29, compute tile ks, issue tile ks+2 (4 VMEM ops).
#pragma unroll 6
    for (int ks = 0; ks < 30; ++ks) {
        const u32 cA = (u32)ks & 1u, nA = cA ^ 1u;
        packA(rA[nA], bufA + nA * 8192u);              // A(ks+1) -> LDS
        loadA(rA[cA], (u32)(ks + 2));                  // 2 ops
        stageB((u32)(ks + 2), bufB + (u32)((ks + 2) % 3) * 16384u);  // 2 ops
        do_mfma(bufA + cA * 8192u, bufB + (u32)(ks % 3) * 16384u);
        asm volatile("s_waitcnt vmcnt(4) lgkmcnt(0)" ::: "memory");
        __builtin_amdgcn_s_barrier();
    }
    // ---- Peel ks=30: pack A(31), no new issues.
    packA(rA[1], bufA + 8192u);
    do_mfma(bufA, bufB);                               // tile 30: bufB[30%3=0]
    asm volatile("s_waitcnt vmcnt(0) lgkmcnt(0)" ::: "memory");
    __builtin_amdgcn_s_barrier();
    // ---- Peel ks=31.
    do_mfma(bufA + 8192u, bufB + 16384u);              // tile 31: bufB[1]

    // rowsum: 4 consecutive threads (t&3) hold k-slices of row sRow
    s0 += __shfl_down(s0, 2, 64);
    s0 += __shfl_down(s0, 1, 64);
    if ((t & 3u) == 0u) sInv[sRow] = (s0 == 0.f) ? 0.f : 1.f / s0;
    __syncthreads();

    u16* pp = partial + (((size_t)(b * 4u + r)) << 18) + (size_t)i0 * 256u;
#pragma unroll
    for (int mt = 0; mt < 4; ++mt)
#pragma unroll
        for (int rg = 0; rg < 4; ++rg) {
            const u32 mRow = wm + (u32)mt * 16u + fg * 4u + (u32)rg;
            const float inv = sInv[mRow];
#pragma unroll
            for (int nt = 0; nt < 4; ++nt)
                pp[(size_t)mRow * 256u + wn + (u32)nt * 16u + fr] =
                    f2h(acc[mt][nt][rg] * inv);
        }
}

// out[b,i,d] = bias[d] + sum_r fp32(partial_h[b,r,i,d]); 8 elems/thread.
__global__ __launch_bounds__(256) void reduce_kernel(const u16* partial,
                                                     const float* bias, float* out) {
    const u32 i8 = blockIdx.x * 256u + threadIdx.x;   // 262144 total
    const u32 b = i8 >> 15;
    const u32 rem8 = (i8 & 32767u) * 8u;              // elem offset within batch
    const u32 d0 = rem8 & 255u;

    const float4 bv0 = *(const float4*)(bias + d0);
    const float4 bv1 = *(const float4*)(bias + d0 + 4u);
    float s[8] = {bv0.x, bv0.y, bv0.z, bv0.w, bv1.x, bv1.y, bv1.z, bv1.w};

#pragma unroll
    for (u32 r = 0; r < 4u; ++r) {
        const uint4 v = *(const uint4*)(partial + (((size_t)(b * 4u + r)) << 18) + rem8);
        const u16* h = (const u16*)&v;
#pragma unroll
        for (int j = 0; j < 8; ++j)
            s[j] += __half2float(__builtin_bit_cast(__half, h[j]));
    }
    const float4 o0 = {s[0], s[1], s[2], s[3]};
    const float4 o1 = {s[4], s[5], s[6], s[7]};
    ((float4*)out)[i8 * 2u] = o0;
    ((float4*)out)[i8 * 2u + 1u] = o1;
}

extern "C" void kernel_launch(void* const* d_in, const int* in_sizes, int n_in,
                              void* d_out, int out_size, void* d_ws, size_t ws_size,
                              hipStream_t stream) {
    const float* text = (const float*)d_in[0];  // [8,1024,256] fp32
    const float* adj  = (const float*)d_in[1];  // [8,4,1024,1024] fp32
    const float* wgt  = (const float*)d_in[2];  // [4,256,256] fp32
    const float* bias = (const float*)d_in[3];  // [256] fp32
    float* out = (float*)d_out;                 // [8,1024,256] fp32

    char* ws = (char*)d_ws;
    u16* Yt      = (u16*)ws;                    // 16 MB  bf16 [B,R,256,1024]
    u16* textb   = (u16*)(ws + 16777216u);      //  4 MB  bf16 [B,N,256]
    u16* Wt      = (u16*)(ws + 20971520u);      // 512 KB bf16 [R,256,256]
    u16* partial = (u16*)(ws + 21495808u);      // 16 MB  fp16 [B,R,N,256]

    prep_cvt_kernel<<<2048, 256, 0, stream>>>(text, textb, wgt, Wt);
    y_gemm_kernel<<<512, 256, 0, stream>>>(Wt, textb, Yt);
    adj_gemm_partial<<<256, 512, 0, stream>>>(adj, Yt, partial);
    reduce_kernel<<<1024, 256, 0, stream>>>(partial, bias, out);
}